// Round 1
// 109.793 us; speedup vs baseline: 1.0545x; 1.0545x over previous
//
#include <hip/hip_runtime.h>
#include <hip/hip_bf16.h>
#include <math.h>

namespace {
typedef __attribute__((ext_vector_type(8)))  short  short8;   // 8 bf16 (MFMA A/B frag)
typedef __attribute__((ext_vector_type(4)))  float  floatx4;  // MFMA C/D frag

constexpr int Bc = 16;    // batch
constexpr int DC = 16;    // deep channels
constexpr int ND = 1024;  // deep length
constexpr int C  = 64;    // c_in
constexpr int N  = 4096;  // sequence
constexpr int CO = 128;   // c_out
constexpr int KW = 7;
constexpr int F  = C * KW;     // 448 (true features)
constexpr int F2 = C * 8;      // 512 (padded: f' = c*8+k, k=7 slot is zero)
constexpr int LT = 32;         // l-tile in k2
constexpr int PLD = F2 + 8;    // 520 shorts/row (1040 B, 16B-aligned rows)
constexpr int GPS = 560;       // per-(b,chunk) Gram slot: G0[256] G1[256] s[16] d0[16] dN[16]
constexpr int NS = F2 / 32;    // 16 K-steps

// workspace layout (bytes)
constexpr size_t WB_OFF = 0;            // swizzled bf16 fc_w: 8192 short8 = 262144
constexpr size_t GP_OFF = 262144;       // 16*8*560*4 = 286720 (ends 548864)

constexpr float EXP2_SCALE = 2.8853900817779268f;   // 2/ln2: exp(-2d) = 2^(-d*2/ln2)

__device__ inline unsigned short f2bf(float f) {
    __hip_bfloat16 h = __float2bfloat16(f);      // RNE
    return __builtin_bit_cast(unsigned short, h);
}
__device__ inline float rcpf(float x) { return __builtin_amdgcn_rcpf(x); }

// K0: blocks [0,32): fc_w fp32 -> bf16, zero-padded + swizzled fragment-major
//     (verified layout: phase-E A-loads are 64-lane contiguous, k=7 slot exact 0).
//     blocks [32,160): per-(b,chunk) Gram partials of deep (verified R5-R7),
//     now float4-vectorized over t: 96 ds_read_b128 instead of 384 ds_read_b32
//     per wave. The t+1 stream (G1) is register-shifted from the t stream; the
//     chunk-boundary tap uses col 128 (staged), and the ch==7 / t==127 term is
//     excluded exactly as in the scalar version (global t <= 1022).
__global__ __launch_bounds__(256)
void k0(const float* __restrict__ deep, const float* __restrict__ fcw,
        unsigned short* __restrict__ wbs, float* __restrict__ gp)
{
    __shared__ __align__(16) float Dch[DC][132];     // cols 0..128 used
    const int blk = blockIdx.x;
    const int tid = threadIdx.x;

    if (blk < 32) {                                  // fc_w swizzle, 8192 short8 total
        const int g    = blk * 256 + tid;
        const int lane = g & 63;
        const int q    = lane >> 4;
        const int rr   = lane & 15;
        const int rest = g >> 6;                     // [0,128)
        const int t    = rest & 1;
        const int sw   = rest >> 1;                  // [0,64)
        const int s    = sw & 15;
        const int w    = sw >> 4;
        const int o    = w * 32 + t * 16 + rr;
        const int c    = s * 4 + q;
        const float* src = fcw + o * F + c * KW;
        const float4 v0 = *(const float4*)(src);       // f0..f3
        const float4 v1 = *(const float4*)(src + 3);   // f3..f6
        short8 h;
        h[0] = (short)f2bf(v0.x); h[1] = (short)f2bf(v0.y);
        h[2] = (short)f2bf(v0.z); h[3] = (short)f2bf(v0.w);
        h[4] = (short)f2bf(v1.y); h[5] = (short)f2bf(v1.z);
        h[6] = (short)f2bf(v1.w); h[7] = 0;            // pad slot (exact no-op)
        ((short8*)wbs)[g] = h;
        return;
    }
    const int i2 = blk - 32;
    const int b  = i2 >> 3;
    const int ch = i2 & 7;
    const int t0 = ch * 128;
    const int d  = tid >> 4;
    const int e  = tid & 15;
#pragma unroll
    for (int p = 0; p < 9; ++p) {
        const int tt = e + 16 * p;
        if (tt < 129)
            Dch[d][tt] = deep[(b * DC + d) * ND + min(t0 + tt, ND - 1)];
    }
    __syncthreads();
    const bool inc3 = (ch != 7);                     // last a1 tap valid iff global t+1 <= 1023
    float a0 = 0.f, a1 = 0.f, as = 0.f;
    float4 Bn = *(const float4*)&Dch[e][0];
#pragma unroll
    for (int t = 0; t < 128; t += 4) {
        const float4 A = *(const float4*)&Dch[d][t];
        const float4 B = Bn;
        Bn = *(const float4*)&Dch[e][t + 4];         // t=124 reads col 128 (valid) + 3 unused
        a0 = fmaf(A.x, B.x, fmaf(A.y, B.y, fmaf(A.z, B.z, fmaf(A.w, B.w, a0))));
        as += (A.x + A.y) + (A.z + A.w);
        a1 = fmaf(A.x, B.y, fmaf(A.y, B.z, fmaf(A.z, B.w, a1)));
        if (t < 124 || inc3) a1 = fmaf(A.w, Bn.x, a1);
    }
    float* gpb = gp + (b * 8 + ch) * GPS;
    gpb[tid] = a0;
    gpb[256 + tid] = a1;
    if (e == 0) {
        gpb[512 + d] = as;
        if (ch == 0) gpb[528 + d] = Dch[d][0];
        if (ch == 7) gpb[544 + d] = Dch[d][127];     // global t=1023
    }
}

// K2: one block per (b, 32-l tile). Four barriers.
//  S (new, absorbs the old ks kernel): every block reduces its batch's Gram
//     partials (gp, L2-resident, ~16 KB/block) to per-(b,c) mc/sc2 in LDS.
//     Redundant x128 but removes the 16-block ks launch + its serialization;
//     the global-load latency hides under the Dw/w/x staging already in flight.
//  A: stage Dw (768 B); per-thread w; PREFETCH interior x window (4x float4)
//     so the VMEM latency hides under the three barriers.
//  D: 6 register V values via float4 ds_read_b128 of Dw; interp w/ compile-time
//     constants (interior) or verified general path (2 edge waves); taps via
//     native exp2 with PAIRED reciprocals (3 v_rcp instead of 6 per l); phi row
//     written as ONE ds_write_b128 per (c,l) thanks to the k=7 zero pad.
//  E: MFMA over 16 K-steps, swizzled coalesced A-loads (verified R7).
__global__ __launch_bounds__(256, 3)
void k2(const float* __restrict__ deep, const float* __restrict__ conv_w,
        const float* __restrict__ conv_b, const float* __restrict__ x,
        const float* __restrict__ gp, const unsigned short* __restrict__ wbs,
        float* __restrict__ out)
{
    __shared__ __align__(16) unsigned short phi[LT * PLD];   // 33280 B
    __shared__ __align__(16) float Dw[12 * 16];              // 768 B
    __shared__ __align__(16) float G0s[256];
    __shared__ __align__(16) float G1s[256];
    __shared__ float ssL[16], dd0L[16], ddNL[16];
    __shared__ float qp[8][64];
    __shared__ float mcL[64], scL[64];                       // +4.8 KB total -> 38.8 KB/block

    const int b   = blockIdx.y;
    const int l0  = blockIdx.x * LT;
    const int t0  = l0 >> 2;
    const int tid = threadIdx.x;
    const int c   = tid & 63;
    const int seg = tid >> 6;

    // ---- S: issue gp reduction loads first (deepest latency to hide) ----
    const float* gpB = gp + (size_t)(b * 8) * GPS;
    float a0 = 0.f, a1 = 0.f;
#pragma unroll
    for (int ch = 0; ch < 8; ++ch) {
        a0 += gpB[ch * GPS + tid];
        a1 += gpB[ch * GPS + 256 + tid];
    }
    float sA = 0.f, d0v = 0.f, dNv = 0.f;
    if (tid < 16) {
#pragma unroll
        for (int ch = 0; ch < 8; ++ch) sA += gpB[ch * GPS + 512 + tid];
        d0v = gpB[528 + tid];                  // ch 0 slot
        dNv = gpB[7 * GPS + 544 + tid];        // ch 7 slot
    }
    const float cb = (tid < 64) ? conv_b[c] : 0.f;

    // ---- A ----
    if (tid < 192) {                                  // deep window [t0-2, t0+9]
        const int ti = tid >> 4, dd = tid & 15;
        const int t = min(max(t0 - 2 + ti, 0), ND - 1);
        Dw[ti * 16 + dd] = deep[(b * DC + dd) * ND + t];
    }
    float w[DC];
    {
        const float4* wr = (const float4*)(conv_w + c * DC);
#pragma unroll
        for (int p = 0; p < 4; ++p) {
            const float4 v = wr[p];
            w[4 * p] = v.x; w[4 * p + 1] = v.y; w[4 * p + 2] = v.z; w[4 * p + 3] = v.w;
        }
    }

    const int base = l0 + seg * 8;
    const bool edge = (blockIdx.x == 0 && seg == 0) ||
                      (blockIdx.x == (N / LT - 1) && seg == 3);
    const float* xr = x + (size_t)(b * C + c) * N;
    float xf[16];
    if (!edge) {                                      // prefetch before barriers
        const float4 x0 = *(const float4*)(xr + base - 4);
        const float4 x1 = *(const float4*)(xr + base);
        const float4 x2 = *(const float4*)(xr + base + 4);
        const float4 x3 = *(const float4*)(xr + base + 8);
        xf[0]=x0.x; xf[1]=x0.y; xf[2]=x0.z; xf[3]=x0.w;
        xf[4]=x1.x; xf[5]=x1.y; xf[6]=x1.z; xf[7]=x1.w;
        xf[8]=x2.x; xf[9]=x2.y; xf[10]=x2.z; xf[11]=x2.w;
        xf[12]=x3.x; xf[13]=x3.y; xf[14]=x3.z; xf[15]=x3.w;
    }

    G0s[tid] = a0; G1s[tid] = a1;
    if (tid < 16) { ssL[tid] = sA; dd0L[tid] = d0v; ddNL[tid] = dNv; }
    __syncthreads();

    // ---- S: quadratic form q = w^T G w, split over 4 parts (== old ks) ----
    {
        float q0 = 0.f, q1 = 0.f;
#pragma unroll
        for (int dd = 0; dd < 4; ++dd) {
            const int d = 4 * seg + dd;
            const float4* g0r = (const float4*)(G0s + d * 16);
            const float4* g1r = (const float4*)(G1s + d * 16);
            float i0 = 0.f, i1 = 0.f;
#pragma unroll
            for (int p = 0; p < 4; ++p) {
                const float4 v0 = g0r[p];
                const float4 v1 = g1r[p];
                i0 = fmaf(w[4*p],   v0.x, i0); i0 = fmaf(w[4*p+1], v0.y, i0);
                i0 = fmaf(w[4*p+2], v0.z, i0); i0 = fmaf(w[4*p+3], v0.w, i0);
                i1 = fmaf(w[4*p],   v1.x, i1); i1 = fmaf(w[4*p+1], v1.y, i1);
                i1 = fmaf(w[4*p+2], v1.z, i1); i1 = fmaf(w[4*p+3], v1.w, i1);
            }
            q0 = fmaf(w[d], i0, q0);
            q1 = fmaf(w[d], i1, q1);
        }
        qp[seg][c] = q0;
        qp[4 + seg][c] = q1;
    }
    __syncthreads();
    if (tid < 64) {
        const float Q0 = qp[0][c] + qp[1][c] + qp[2][c] + qp[3][c];
        const float Q1 = qp[4][c] + qp[5][c] + qp[6][c] + qp[7][c];
        float wS = 0.f, V0 = 0.f, VN = 0.f;
#pragma unroll
        for (int d = 0; d < DC; ++d) {
            wS = fmaf(w[d], ssL[d],  wS);
            V0 = fmaf(w[d], dd0L[d], V0);
            VN = fmaf(w[d], ddNL[d], VN);
        }
        const float mean = wS * (1.f / 1024.f) + cb;
        const float S2   = 2.625f * Q0 + 1.375f * Q1 + 0.6875f * (V0 * V0 + VN * VN)
                         + 8.f * cb * wS + 4096.f * cb * cb;
        const float var  = (S2 - 4096.f * mean * mean) * (1.f / 4095.f);   // ddof=1
        mcL[c] = wS * (1.f / 1024.f);
        scL[c] = (0.5f / (var + 1e-9f)) * EXP2_SCALE;
    }
    __syncthreads();
    const float mc  = mcL[c];
    const float sc2 = scL[c];

    // ---- D ----
    {
        float Vr[6];                          // covers every interp tap in window
#pragma unroll
        for (int m = 0; m < 6; ++m) {
            const float4* dr4 = (const float4*)(Dw + (2 * seg + m) * 16);
            float a = 0.f;
#pragma unroll
            for (int p = 0; p < 4; ++p) {
                const float4 v = dr4[p];
                a = fmaf(w[4*p],   v.x, a); a = fmaf(w[4*p+1], v.y, a);
                a = fmaf(w[4*p+2], v.z, a); a = fmaf(w[4*p+3], v.w, a);
            }
            Vr[m] = a;
        }
        const float WA[4] = {0.375f, 0.125f, 0.875f, 0.625f};
        float xsv[14], xvf[14];
        if (!edge) {
#pragma unroll
            for (int i = 0; i < 14; ++i) {
                const int r  = (i + 1) & 3;                    // (base-3+i)&3, base%4==0
                const int ma = ((i + 5) >> 2) - 1 + (r >> 1);  // V index rel. tbase
                const float wa = WA[r];
                xsv[i] = (fmaf(wa, Vr[ma], (1.f - wa) * Vr[ma + 1]) - mc) * sc2;
                xvf[i] = xf[1 + i];
            }
        } else {                                       // verified general path
            const int tbase = t0 + 2 * seg - 2;
#pragma unroll
            for (int i = 0; i < 14; ++i) {
                const int j  = base - 3 + i;
                const int ja = (j < 0) ? -j : j;
                const int jr = min(ja, 2 * N - 2 - ja);        // reflect
                const int t  = jr >> 2;
                const int r  = jr & 3;
                const float wa = WA[r];
                int tA = t - 1 + (r >> 1);
                int tB = tA + 1;
                if (tA < 0) { tA = 0; tB = 0; }   // src clipped to 0 -> V[0] exactly
                if (tB > ND - 1) tB = ND - 1;     // src clipped to 1023 -> V[1023]
                const int ia = tA - tbase;
                const int ib = tB - tbase;
                xsv[i] = (wa * Vr[ia] + (1.f - wa) * Vr[ib] - mc) * sc2;
                xvf[i] = xr[jr];
            }
        }
        unsigned short* pcol = phi + c * 8;
#pragma unroll
        for (int li = 0; li < 8; ++li) {
            const float cen = xsv[li + 3];
            float ev[6], t2[6];                // taps k = {0,1,2,4,5,6}
#pragma unroll
            for (int j = 0; j < 6; ++j) {
                const int k = (j < 3) ? j : j + 1;
                const float d = fabsf(xsv[li + k] - cen);     // already * 2/ln2
                const float e = __builtin_amdgcn_exp2f(-d);   // = exp(-2*d_true)
                const float t = 1.f + e;
                ev[j] = e; t2[j] = t * t;
            }
            float u[KW];
            u[3] = 0.25f;                      // center tap: d=0 -> loss/4 = 1/4 exactly
            float s = 0.25f;
#pragma unroll
            for (int pr = 0; pr < 3; ++pr) {   // paired reciprocals: 3 rcp, not 6
                const int ja = 2 * pr, jb = 2 * pr + 1;
                const float r  = rcpf(t2[ja] * t2[jb]);
                const float ua = ev[ja] * t2[jb] * r;          // = e/(1+e)^2 = loss/4
                const float ub = ev[jb] * t2[ja] * r;
                const int ka = (ja < 3) ? ja : ja + 1;
                const int kb = (jb < 3) ? jb : jb + 1;
                u[ka] = ua; u[kb] = ub;
                s += ua + ub;
            }
            const float al = rcpf(s);
            short8 ph;
#pragma unroll
            for (int k = 0; k < KW; ++k) ph[k] = (short)f2bf(u[k] * al * xvf[li + k]);
            ph[7] = 0;                                         // pad slot
            *(short8*)(pcol + (seg * 8 + li) * PLD) = ph;      // one b128 write
        }
    }
    __syncthreads();

    // ---- E: MFMA, swizzled coalesced A-loads, fully unrolled, 16 K-steps ----
    const int lane = tid & 63;
    const int quad = lane >> 4;
    const int rr   = lane & 15;
    const int o0   = seg * 32;

    floatx4 acc00 = {0.f, 0.f, 0.f, 0.f}, acc01 = acc00, acc10 = acc00, acc11 = acc00;
    const short8* wp = (const short8*)wbs + (size_t)seg * (NS * 2 * 64) + lane;
    const unsigned short* prow0 = phi + rr * PLD + quad * 8;
    const unsigned short* prow1 = prow0 + 16 * PLD;

#pragma unroll
    for (int s = 0; s < NS; ++s) {
        const int f0 = 32 * s;
        const short8 a0f = wp[s * 128];         // 64 lanes x 16 B contiguous
        const short8 a1f = wp[s * 128 + 64];
        const short8 b0f = *(const short8*)(prow0 + f0);
        const short8 b1f = *(const short8*)(prow1 + f0);
        acc00 = __builtin_amdgcn_mfma_f32_16x16x32_bf16(a0f, b0f, acc00, 0, 0, 0);
        acc01 = __builtin_amdgcn_mfma_f32_16x16x32_bf16(a0f, b1f, acc01, 0, 0, 0);
        acc10 = __builtin_amdgcn_mfma_f32_16x16x32_bf16(a1f, b0f, acc10, 0, 0, 0);
        acc11 = __builtin_amdgcn_mfma_f32_16x16x32_bf16(a1f, b1f, acc11, 0, 0, 0);
    }

    float* ob = out + (size_t)(b * CO) * N + l0;
#pragma unroll
    for (int i = 0; i < 4; ++i) {
        const int om = quad * 4 + i;
        ob[(o0 + om) * N      + rr     ] = acc00[i];
        ob[(o0 + om) * N      + 16 + rr] = acc01[i];
        ob[(o0 + 16 + om) * N + rr     ] = acc10[i];
        ob[(o0 + 16 + om) * N + 16 + rr] = acc11[i];
    }
}
} // namespace

extern "C" void kernel_launch(void* const* d_in, const int* in_sizes, int n_in,
                              void* d_out, int out_size, void* d_ws, size_t ws_size,
                              hipStream_t stream)
{
    const float* deep   = (const float*)d_in[0];
    const float* x      = (const float*)d_in[1];
    const float* conv_w = (const float*)d_in[2];
    const float* conv_b = (const float*)d_in[3];
    const float* fc_w   = (const float*)d_in[4];
    float* out = (float*)d_out;

    unsigned short* wbuf = (unsigned short*)((char*)d_ws + WB_OFF);
    float*          gp   = (float*)((char*)d_ws + GP_OFF);

    hipLaunchKernelGGL(k0, dim3(32 + 128), dim3(256), 0, stream,
                       deep, fc_w, wbuf, gp);
    hipLaunchKernelGGL(k2, dim3(N / LT, Bc), dim3(256), 0, stream,
                       deep, conv_w, conv_b, x, gp, wbuf, out);
}